// Round 14
// baseline (276.189 us; speedup 1.0000x reference)
//
#include <hip/hip_runtime.h>

typedef __bf16 bf16x8 __attribute__((ext_vector_type(8)));
typedef float  f32x4  __attribute__((ext_vector_type(4)));

constexpr int BM = 128, BN = 128, BK = 32;
constexpr int MDIM = 65536, NDIM = 1152, KDIM = 768;
constexpr int NBN = NDIM / BN;          // 9
constexpr int NKT = KDIM / BK;          // 24
constexpr int GRID = (MDIM / BM) * NBN; // 4608 (div by 8 -> bijective XCD swizzle)
constexpr int LDSROWB = BK * 2;         // 64 B per tile row (32 bf16)
constexpr int CHUNKS_A = (MDIM / BM) * NKT * 512;  // 6,291,456 16B chunks
constexpr int CHUNKS_W = NBN * NKT * 512;          //   110,592

__device__ __forceinline__ void gload16(const void* g, void* l) {
  __builtin_amdgcn_global_load_lds(
      (const __attribute__((address_space(1))) void*)g,
      (__attribute__((address_space(3))) void*)l, 16, 0, 0);
}

__device__ __forceinline__ unsigned pk2(float x, float y) {
  __bf16 a = (__bf16)x, b = (__bf16)y;
  return (unsigned)__builtin_bit_cast(unsigned short, a) |
         ((unsigned)__builtin_bit_cast(unsigned short, b) << 16);
}

// ------- fp32 -> bf16 FRAGMENT-MAJOR image repack, A and W in ONE launch (R12) -------
__global__ __launch_bounds__(256)
void repack_all_kernel(const float* __restrict__ Ain, __bf16* __restrict__ Aout,
                       const float* __restrict__ Win, __bf16* __restrict__ Wout) {
  int c = blockIdx.x * 256 + threadIdx.x;
  const float* in;
  __bf16* out;
  if (c < CHUNKS_A) { in = Ain; out = Aout; }
  else              { in = Win; out = Wout; c -= CHUNKS_A; }
  const int c_in = c & 511;        // 16B chunk within 8KB image
  const int img  = c >> 9;
  const int kt   = img % NKT;
  const int pan  = img / NKT;      // 128-row panel index
  const int r16  = c_in >> 6;      // fragment 0..7
  const int ln   = c_in & 63;      // lane within fragment
  const int kg   = ln >> 4;
  const int fr   = ln & 15;
  const float* src = in + (size_t)(pan * 128 + r16 * 16 + fr) * KDIM + kt * 32 + kg * 8;
  const float4 x = *reinterpret_cast<const float4*>(src);
  const float4 y = *reinterpret_cast<const float4*>(src + 4);
  uint4 r4;
  r4.x = pk2(x.x, x.y); r4.y = pk2(x.z, x.w);
  r4.z = pk2(y.x, y.y); r4.w = pk2(y.z, y.w);
  *reinterpret_cast<uint4*>(out + (size_t)c * 8) = r4;
}

// -------- main GEMM: A via gload_lds (frag-major LDS), B via global->reg (L2-hot) ----
__global__ __launch_bounds__(256, 3)
void gemm_breg_kernel(const __bf16* __restrict__ Aimg,  // [512][24][8KB] frag-major
                      const __bf16* __restrict__ Bimg,  // [9][24][8KB] frag-major
                      const int*   __restrict__ ss,
                      const float* __restrict__ bias,
                      const float* __restrict__ pos,
                      float* __restrict__ out) {
  // 32 KB pool: A double-buffer (16 KB) during K-loop; fp32 Cs in epilogue
  __shared__ __align__(16) unsigned char SM[32768];
  __bf16* As0 = reinterpret_cast<__bf16*>(SM);            // As[0]: 8KB, As[1]: 8KB
  float*  Cs  = reinterpret_cast<float*>(SM);             // 64 x 128 fp32 (epilogue)

  const int tid  = threadIdx.x;
  const int lane = tid & 63;
  const int wid  = tid >> 6;
  const int wr   = wid >> 1;
  const int wc   = wid & 1;

  const int bidh = blockIdx.x;
  const int bid  = (bidh & 7) * (GRID / 8) + (bidh >> 3);
  const int bm   = bid / NBN;
  const int bn   = bid % NBN;

  auto stageA = [&](int kt, int buf) {       // 2 gload16 per thread (8 KB total)
    const __bf16* wsA = Aimg + ((size_t)(bm * NKT + kt) << 12);  // 4096 bf16 / image
    char* la = (char*)As0 + buf * 8192;
    gload16(wsA + tid * 8,         la + tid * 16);
    gload16(wsA + (256 + tid) * 8, la + (256 + tid) * 16);
  };

  // B fragments straight from L2: lane-linear 16B/lane, coalesced 1KB per wave read
  const __bf16* Bbase = Bimg + ((size_t)(bn * NKT) << 12) + wc * 2048 + lane * 8;
  auto loadB = [&](bf16x8* d, int kt) {
    const __bf16* p = Bbase + ((size_t)kt << 12);
#pragma unroll
    for (int nf = 0; nf < 4; ++nf)
      d[nf] = *reinterpret_cast<const bf16x8*>(p + nf * 512);
  };

  f32x4 acc[4][4];
#pragma unroll
  for (int i = 0; i < 4; ++i)
#pragma unroll
    for (int j = 0; j < 4; ++j) acc[i][j] = (f32x4)0.0f;

  const int fr = lane & 15;
  const int kg = lane >> 4;
  const int abase = wr * 4096 + lane * 16;   // fragment (wr*4+mf), lane-linear

  auto compute = [&](int buf, const bf16x8* bfv) {
    const char* pa = (const char*)As0 + buf * 8192 + abase;
    bf16x8 af[4];
#pragma unroll
    for (int mf = 0; mf < 4; ++mf)
      af[mf] = *reinterpret_cast<const bf16x8*>(pa + mf * 1024);
#pragma unroll
    for (int mf = 0; mf < 4; ++mf)
#pragma unroll
      for (int nf = 0; nf < 4; ++nf)
        acc[mf][nf] = __builtin_amdgcn_mfma_f32_16x16x32_bf16(af[mf], bfv[nf], acc[mf][nf], 0, 0, 0);
  };

  // 2-barrier loop (R11-verified), unrolled x2 for static b0/b1 double-buffer.
  // B(kt+1) issued right after the barrier; consumed after the NEXT barrier ->
  // one full compute phase covers its L2 latency (compiler inserts the vmcnt).
  bf16x8 b0[4], b1[4];
  stageA(0, 0);
  loadB(b0, 0);
  for (int k2 = 0; k2 < NKT; k2 += 2) {
    __syncthreads();                              // drains stageA(k2) for all waves
    if (k2 + 1 < NKT) { stageA(k2 + 1, 1); loadB(b1, k2 + 1); }
    compute(0, b0);
    __syncthreads();                              // drains stageA(k2+1)
    if (k2 + 2 < NKT) { stageA(k2 + 2, 0); loadB(b0, k2 + 2); }
    compute(1, b1);
  }

  // ------------- epilogue: LDS transpose -> f32x4 pos gathers + full-line stores ----
  const int chunk = tid & 15;
  const int gcol  = bn * BN + chunk * 8;
  const f32x4 bias_lo = *reinterpret_cast<const f32x4*>(bias + gcol);
  const f32x4 bias_hi = *reinterpret_cast<const f32x4*>(bias + gcol + 4);

  const int s  = bm >> 3;
  const int h  = ss[2 * s];
  const int w  = ss[2 * s + 1];
  const int hw = h * w;
  const float rh = 16.0f / (float)h;
  const float rw = 16.0f / (float)w;

#pragma unroll
  for (int half = 0; half < 2; ++half) {
    __syncthreads();   // K-loop reads done (half 0) / prev half's reads done (half 1)
#pragma unroll
    for (int mm = 0; mm < 2; ++mm) {
#pragma unroll
      for (int nf = 0; nf < 4; ++nf) {
#pragma unroll
        for (int rg = 0; rg < 4; ++rg) {
          const int rowL = wr * 32 + mm * 16 + kg * 4 + rg;          // 0..63
          const int col  = wc * 64 + nf * 16 + fr;                   // 0..127
          const int key  = (rowL & 3) ^ ((rowL >> 2) & 3);
          Cs[(rowL << 7) + (col ^ (key << 3))] = acc[half * 2 + mm][nf][rg];
        }
      }
    }
    __syncthreads();
#pragma unroll
    for (int pass = 0; pass < 4; ++pass) {
      const int rowL = pass * 16 + (tid >> 4);
      const int key  = (rowL & 3) ^ ((rowL >> 2) & 3);
      const float* crow = Cs + (rowL << 7) + ((chunk ^ key) << 3);
      const f32x4 c0 = *reinterpret_cast<const f32x4*>(crow);
      const f32x4 c1 = *reinterpret_cast<const f32x4*>(crow + 4);

      const int grow = bm * BM + (rowL >> 5) * 64 + half * 32 + (rowL & 31);
      int p = grow & 1023;
      if (p >= hw) p = 0;          // padded region replicates resized[0] == grid[0,0]
      const int y = p / w;
      const int x = p - y * w;
      const float fy = ((float)y + 0.5f) * rh - 0.5f;
      const float fx = ((float)x + 0.5f) * rw - 0.5f;
      const float yf = floorf(fy), xf = floorf(fx);
      const float ty = fy - yf,   tx = fx - xf;
      int iy0 = (int)yf, ix0 = (int)xf;
      int iy1 = iy0 + 1 > 15 ? 15 : iy0 + 1;
      int ix1 = ix0 + 1 > 15 ? 15 : ix0 + 1;
      iy0 = iy0 < 0 ? 0 : iy0;
      ix0 = ix0 < 0 ? 0 : ix0;
      const float* g00 = pos + (size_t)(iy0 * 16 + ix0) * NDIM + gcol;
      const float* g01 = pos + (size_t)(iy0 * 16 + ix1) * NDIM + gcol;
      const float* g10 = pos + (size_t)(iy1 * 16 + ix0) * NDIM + gcol;
      const float* g11 = pos + (size_t)(iy1 * 16 + ix1) * NDIM + gcol;

      const f32x4 v00l = *reinterpret_cast<const f32x4*>(g00);
      const f32x4 v01l = *reinterpret_cast<const f32x4*>(g01);
      const f32x4 v10l = *reinterpret_cast<const f32x4*>(g10);
      const f32x4 v11l = *reinterpret_cast<const f32x4*>(g11);
      const f32x4 v00h = *reinterpret_cast<const f32x4*>(g00 + 4);
      const f32x4 v01h = *reinterpret_cast<const f32x4*>(g01 + 4);
      const f32x4 v10h = *reinterpret_cast<const f32x4*>(g10 + 4);
      const f32x4 v11h = *reinterpret_cast<const f32x4*>(g11 + 4);

      const f32x4 topl = v00l + tx * (v01l - v00l);
      const f32x4 botl = v10l + tx * (v11l - v10l);
      const f32x4 pvl  = topl + ty * (botl - topl);
      const f32x4 toph = v00h + tx * (v01h - v00h);
      const f32x4 both = v10h + tx * (v11h - v10h);
      const f32x4 pvh  = toph + ty * (both - toph);

      float* orow = out + (size_t)grow * NDIM + gcol;
      *reinterpret_cast<f32x4*>(orow)     = c0 + bias_lo + pvl;
      *reinterpret_cast<f32x4*>(orow + 4) = c1 + bias_hi + pvh;
    }
  }
}

// ---------------- fallback: fp32 inputs, reg-stage + on-the-fly convert (known-good) ----
__global__ __launch_bounds__(256, 2)
void gemm_fb_kernel(const float* __restrict__ A,
                    const int*   __restrict__ ss,
                    const float* __restrict__ Wm,
                    const float* __restrict__ bias,
                    const float* __restrict__ pos,
                    float* __restrict__ out) {
  __shared__ unsigned short As[2][BM * BK];
  __shared__ unsigned short Bs[2][BM * BK];

  const int tid  = threadIdx.x;
  const int lane = tid & 63;
  const int wid  = tid >> 6;
  const int wr   = wid >> 1;
  const int wc   = wid & 1;

  const int bidh = blockIdx.x;
  const int bid  = (bidh & 7) * (GRID / 8) + (bidh >> 3);
  const int bm   = bid / NBN;
  const int bn   = bid % NBN;

  const int srow0 = tid >> 3;
  const int skc   = tid & 7;
  const float* Ag = A  + (size_t)(bm * BM + srow0) * KDIM + skc * 4;
  const float* Bg = Wm + (size_t)(bn * BN + srow0) * KDIM + skc * 4;

  float4 ra[4], rb[4];

  auto stage_load = [&](int kt) {
    const int ko = kt * BK;
#pragma unroll
    for (int r = 0; r < 4; ++r) {
      ra[r] = *reinterpret_cast<const float4*>(Ag + (size_t)(r * 32) * KDIM + ko);
      rb[r] = *reinterpret_cast<const float4*>(Bg + (size_t)(r * 32) * KDIM + ko);
    }
  };

  auto stage_write = [&](int buf) {
#pragma unroll
    for (int r = 0; r < 4; ++r) {
      const int arow = r * 32 + srow0;
      int off = arow * LDSROWB + skc * 8;
      off ^= (arow & 7) << 4;
      uint2 pa, pb;
      pa.x = pk2(ra[r].x, ra[r].y); pa.y = pk2(ra[r].z, ra[r].w);
      pb.x = pk2(rb[r].x, rb[r].y); pb.y = pk2(rb[r].z, rb[r].w);
      *reinterpret_cast<uint2*>(reinterpret_cast<char*>(&As[buf][0]) + off) = pa;
      *reinterpret_cast<uint2*>(reinterpret_cast<char*>(&Bs[buf][0]) + off) = pb;
    }
  };

  f32x4 acc[4][4];
#pragma unroll
  for (int i = 0; i < 4; ++i)
#pragma unroll
    for (int j = 0; j < 4; ++j) acc[i][j] = (f32x4)0.0f;

  const int fr = lane & 15;
  const int kg = lane >> 4;
  int abase = (wr * 64 + fr) * LDSROWB + kg * 16; abase ^= (fr & 7) << 4;
  int bbase = (wc * 64 + fr) * LDSROWB + kg * 16; bbase ^= (fr & 7) << 4;

  auto compute = [&](int buf) {
    const char* pa = reinterpret_cast<const char*>(&As[buf][0]);
    const char* pb = reinterpret_cast<const char*>(&Bs[buf][0]);
    bf16x8 af[4], bfv[4];
#pragma unroll
    for (int mf = 0; mf < 4; ++mf)
      af[mf] = *reinterpret_cast<const bf16x8*>(pa + abase + mf * 16 * LDSROWB);
#pragma unroll
    for (int nf = 0; nf < 4; ++nf)
      bfv[nf] = *reinterpret_cast<const bf16x8*>(pb + bbase + nf * 16 * LDSROWB);
#pragma unroll
    for (int mf = 0; mf < 4; ++mf)
#pragma unroll
      for (int nf = 0; nf < 4; ++nf)
        acc[mf][nf] = __builtin_amdgcn_mfma_f32_16x16x32_bf16(af[mf], bfv[nf], acc[mf][nf], 0, 0, 0);
  };

  stage_load(0);
  stage_write(0);
  for (int kt = 0; kt < NKT; ++kt) {
    const int cur = kt & 1;
    if (kt + 1 < NKT) stage_load(kt + 1);
    __syncthreads();
    compute(cur);
    if (kt + 1 < NKT) stage_write(cur ^ 1);
  }

  const int colbase = bn * BN + wc * 64 + fr;
  float bvals[4];
#pragma unroll
  for (int nf = 0; nf < 4; ++nf) bvals[nf] = bias[colbase + nf * 16];

  const int s  = bm >> 3;
  const int h  = ss[2 * s];
  const int w  = ss[2 * s + 1];
  const int hw = h * w;
  const float rh = 16.0f / (float)h;
  const float rw = 16.0f / (float)w;
  const int row0 = bm * BM + wr * 64 + kg * 4;

#pragma unroll
  for (int mf = 0; mf < 4; ++mf) {
#pragma unroll
    for (int rg = 0; rg < 4; ++rg) {
      const int row = row0 + mf * 16 + rg;
      int p = row & 1023;
      if (p >= hw) p = 0;
      const int y = p / w;
      const int x = p - y * w;
      const float fy = ((float)y + 0.5f) * rh - 0.5f;
      const float fx = ((float)x + 0.5f) * rw - 0.5f;
      const float yf = floorf(fy), xf = floorf(fx);
      const float ty = fy - yf,   tx = fx - xf;
      int iy0 = (int)yf, ix0 = (int)xf;
      int iy1 = iy0 + 1 > 15 ? 15 : iy0 + 1;
      int ix1 = ix0 + 1 > 15 ? 15 : ix0 + 1;
      iy0 = iy0 < 0 ? 0 : iy0;
      ix0 = ix0 < 0 ? 0 : ix0;
      const float* g00 = pos + (size_t)(iy0 * 16 + ix0) * NDIM;
      const float* g01 = pos + (size_t)(iy0 * 16 + ix1) * NDIM;
      const float* g10 = pos + (size_t)(iy1 * 16 + ix0) * NDIM;
      const float* g11 = pos + (size_t)(iy1 * 16 + ix1) * NDIM;
      float* orow = out + (size_t)row * NDIM;
#pragma unroll
      for (int nf = 0; nf < 4; ++nf) {
        const int col = colbase + nf * 16;
        const float p00 = g00[col], p01 = g01[col];
        const float p10 = g10[col], p11 = g11[col];
        const float top = p00 + tx * (p01 - p00);
        const float bot = p10 + tx * (p11 - p10);
        const float pv  = top + ty * (bot - top);
        orow[col] = acc[mf][nf][rg] + bvals[nf] + pv;
      }
    }
  }
}

extern "C" void kernel_launch(void* const* d_in, const int* in_sizes, int n_in,
                              void* d_out, int out_size, void* d_ws, size_t ws_size,
                              hipStream_t stream) {
  const float* A    = (const float*)d_in[0];
  const int*   ss   = (const int*)d_in[1];
  const float* Wm   = (const float*)d_in[2];
  const float* bias = (const float*)d_in[3];
  const float* pos  = (const float*)d_in[4];
  float* out = (float*)d_out;

  const size_t needA = (size_t)MDIM * KDIM * 2;  // 100,663,296 B
  const size_t needW = (size_t)NDIM * KDIM * 2;  //   1,769,472 B

  if (ws_size >= needA + needW) {
    __bf16* Ab = (__bf16*)d_ws;
    __bf16* Bb = (__bf16*)((char*)d_ws + needA);
    repack_all_kernel<<<(CHUNKS_A + CHUNKS_W) / 256, 256, 0, stream>>>(A, Ab, Wm, Bb);
    gemm_breg_kernel<<<GRID, 256, 0, stream>>>(Ab, Bb, ss, bias, pos, out);
  } else {
    gemm_fb_kernel<<<GRID, 256, 0, stream>>>(A, ss, Wm, bias, pos, out);
  }
}

// Round 15
// 259.879 us; speedup vs baseline: 1.0628x; 1.0628x over previous
//
#include <hip/hip_runtime.h>

typedef __bf16 bf16x8 __attribute__((ext_vector_type(8)));
typedef float  f32x4  __attribute__((ext_vector_type(4)));

constexpr int BM = 128, BN = 128, BK = 32;
constexpr int MDIM = 65536, NDIM = 1152, KDIM = 768;
constexpr int NBN = NDIM / BN;          // 9
constexpr int NKT = KDIM / BK;          // 24
constexpr int GRID = (MDIM / BM) * NBN; // 4608 (div by 8 -> bijective XCD swizzle)
constexpr int LDSROWB = BK * 2;         // 64 B per tile row (32 bf16)
constexpr int CHUNKS_A = (MDIM / BM) * NKT * 512;  // 6,291,456 16B chunks
constexpr int CHUNKS_W = NBN * NKT * 512;          //   110,592

__device__ __forceinline__ void gload16(const void* g, void* l) {
  __builtin_amdgcn_global_load_lds(
      (const __attribute__((address_space(1))) void*)g,
      (__attribute__((address_space(3))) void*)l, 16, 0, 0);
}

__device__ __forceinline__ unsigned pk2(float x, float y) {
  __bf16 a = (__bf16)x, b = (__bf16)y;
  return (unsigned)__builtin_bit_cast(unsigned short, a) |
         ((unsigned)__builtin_bit_cast(unsigned short, b) << 16);
}

// ------- fp32 -> bf16 FRAGMENT-MAJOR image repack, A and W in ONE launch (R12) -------
__global__ __launch_bounds__(256)
void repack_all_kernel(const float* __restrict__ Ain, __bf16* __restrict__ Aout,
                       const float* __restrict__ Win, __bf16* __restrict__ Wout) {
  int c = blockIdx.x * 256 + threadIdx.x;
  const float* in;
  __bf16* out;
  if (c < CHUNKS_A) { in = Ain; out = Aout; }
  else              { in = Win; out = Wout; c -= CHUNKS_A; }
  const int c_in = c & 511;        // 16B chunk within 8KB image
  const int img  = c >> 9;
  const int kt   = img % NKT;
  const int pan  = img / NKT;      // 128-row panel index
  const int r16  = c_in >> 6;      // fragment 0..7
  const int ln   = c_in & 63;      // lane within fragment
  const int kg   = ln >> 4;
  const int fr   = ln & 15;
  const float* src = in + (size_t)(pan * 128 + r16 * 16 + fr) * KDIM + kt * 32 + kg * 8;
  const float4 x = *reinterpret_cast<const float4*>(src);
  const float4 y = *reinterpret_cast<const float4*>(src + 4);
  uint4 r4;
  r4.x = pk2(x.x, x.y); r4.y = pk2(x.z, x.w);
  r4.z = pk2(y.x, y.y); r4.w = pk2(y.z, y.w);
  *reinterpret_cast<uint4*>(out + (size_t)c * 8) = r4;
}

// -------- main GEMM: R12 verbatim except __launch_bounds__(256,4) (occupancy A/B) ----
__global__ __launch_bounds__(256, 4)
void gemm_fm2_kernel(const __bf16* __restrict__ Aimg,  // [512][24][8KB] frag-major images
                     const __bf16* __restrict__ Bimg,  // [9][24][8KB]
                     const int*   __restrict__ ss,
                     const float* __restrict__ bias,
                     const float* __restrict__ pos,
                     float* __restrict__ out) {
  // single 32 KB pool: tiles during K-loop, fp32 transpose buffer in epilogue
  __shared__ __align__(16) unsigned char SM[32768];
  __bf16* As0 = reinterpret_cast<__bf16*>(SM);            // As[0]: 8KB, As[1]: 8KB
  __bf16* Bs0 = reinterpret_cast<__bf16*>(SM + 16384);    // Bs[0], Bs[1]
  float*  Cs  = reinterpret_cast<float*>(SM);             // 64 x 128 fp32 (epilogue)

  const int tid  = threadIdx.x;
  const int lane = tid & 63;
  const int wid  = tid >> 6;
  const int wr   = wid >> 1;
  const int wc   = wid & 1;

  const int bidh = blockIdx.x;
  const int bid  = (bidh & 7) * (GRID / 8) + (bidh >> 3);
  const int bm   = bid / NBN;
  const int bn   = bid % NBN;

  auto stage = [&](int kt, int buf) {
    const __bf16* wsA = Aimg + ((size_t)(bm * NKT + kt) << 12);  // 4096 bf16 / image
    const __bf16* wsB = Bimg + ((size_t)(bn * NKT + kt) << 12);
    char* la = (char*)As0 + buf * 8192;
    char* lb = (char*)Bs0 + buf * 8192;
    gload16(wsA + tid * 8,         la + tid * 16);
    gload16(wsA + (256 + tid) * 8, la + (256 + tid) * 16);
    gload16(wsB + tid * 8,         lb + tid * 16);
    gload16(wsB + (256 + tid) * 8, lb + (256 + tid) * 16);
  };

  f32x4 acc[4][4];
#pragma unroll
  for (int i = 0; i < 4; ++i)
#pragma unroll
    for (int j = 0; j < 4; ++j) acc[i][j] = (f32x4)0.0f;

  const int fr = lane & 15;
  const int kg = lane >> 4;
  // frag-major: fragment (wr*4+mf) of the A image at +1KB strides, lane-linear
  const int abase = wr * 4096 + lane * 16;
  const int bbase = wc * 4096 + lane * 16;

  auto compute = [&](int buf) {
    const char* pa = (const char*)As0 + buf * 8192 + abase;
    const char* pb = (const char*)Bs0 + buf * 8192 + bbase;
    bf16x8 af[4], bfv[4];
#pragma unroll
    for (int mf = 0; mf < 4; ++mf)
      af[mf] = *reinterpret_cast<const bf16x8*>(pa + mf * 1024);
#pragma unroll
    for (int nf = 0; nf < 4; ++nf)
      bfv[nf] = *reinterpret_cast<const bf16x8*>(pb + nf * 1024);
#pragma unroll
    for (int mf = 0; mf < 4; ++mf)
#pragma unroll
      for (int nf = 0; nf < 4; ++nf)
        acc[mf][nf] = __builtin_amdgcn_mfma_f32_16x16x32_bf16(af[mf], bfv[nf], acc[mf][nf], 0, 0, 0);
  };

  stage(0, 0);
  for (int kt = 0; kt < NKT; ++kt) {
    const int cur = kt & 1;
    __syncthreads();                           // drains stage of buf[cur]
    if (kt + 1 < NKT) stage(kt + 1, cur ^ 1);  // async prefetch flies under MFMA
    compute(cur);
  }

  // ------------- epilogue: LDS transpose -> f32x4 pos gathers + full-line stores ----
  const int chunk = tid & 15;
  const int gcol  = bn * BN + chunk * 8;
  const f32x4 bias_lo = *reinterpret_cast<const f32x4*>(bias + gcol);
  const f32x4 bias_hi = *reinterpret_cast<const f32x4*>(bias + gcol + 4);

  const int s  = bm >> 3;
  const int h  = ss[2 * s];
  const int w  = ss[2 * s + 1];
  const int hw = h * w;
  const float rh = 16.0f / (float)h;
  const float rw = 16.0f / (float)w;

#pragma unroll
  for (int half = 0; half < 2; ++half) {
    __syncthreads();   // K-loop reads done (half 0) / prev half's reads done (half 1)
    // ---- write phase: col-major acc quads -> swizzled Cs[64][128] ----
#pragma unroll
    for (int mm = 0; mm < 2; ++mm) {
#pragma unroll
      for (int nf = 0; nf < 4; ++nf) {
#pragma unroll
        for (int rg = 0; rg < 4; ++rg) {
          const int rowL = wr * 32 + mm * 16 + kg * 4 + rg;          // 0..63
          const int col  = wc * 64 + nf * 16 + fr;                   // 0..127
          const int key  = (rowL & 3) ^ ((rowL >> 2) & 3);
          Cs[(rowL << 7) + (col ^ (key << 3))] = acc[half * 2 + mm][nf][rg];
        }
      }
    }
    __syncthreads();
    // ---- read + process: 4 passes x (16 rows x 128 cols) ----
#pragma unroll
    for (int pass = 0; pass < 4; ++pass) {
      const int rowL = pass * 16 + (tid >> 4);
      const int key  = (rowL & 3) ^ ((rowL >> 2) & 3);
      const float* crow = Cs + (rowL << 7) + ((chunk ^ key) << 3);
      const f32x4 c0 = *reinterpret_cast<const f32x4*>(crow);
      const f32x4 c1 = *reinterpret_cast<const f32x4*>(crow + 4);

      const int grow = bm * BM + (rowL >> 5) * 64 + half * 32 + (rowL & 31);
      int p = grow & 1023;
      if (p >= hw) p = 0;          // padded region replicates resized[0] == grid[0,0]
      const int y = p / w;
      const int x = p - y * w;
      const float fy = ((float)y + 0.5f) * rh - 0.5f;
      const float fx = ((float)x + 0.5f) * rw - 0.5f;
      const float yf = floorf(fy), xf = floorf(fx);
      const float ty = fy - yf,   tx = fx - xf;
      int iy0 = (int)yf, ix0 = (int)xf;
      int iy1 = iy0 + 1 > 15 ? 15 : iy0 + 1;
      int ix1 = ix0 + 1 > 15 ? 15 : ix0 + 1;
      iy0 = iy0 < 0 ? 0 : iy0;
      ix0 = ix0 < 0 ? 0 : ix0;
      const float* g00 = pos + (size_t)(iy0 * 16 + ix0) * NDIM + gcol;
      const float* g01 = pos + (size_t)(iy0 * 16 + ix1) * NDIM + gcol;
      const float* g10 = pos + (size_t)(iy1 * 16 + ix0) * NDIM + gcol;
      const float* g11 = pos + (size_t)(iy1 * 16 + ix1) * NDIM + gcol;

      const f32x4 v00l = *reinterpret_cast<const f32x4*>(g00);
      const f32x4 v01l = *reinterpret_cast<const f32x4*>(g01);
      const f32x4 v10l = *reinterpret_cast<const f32x4*>(g10);
      const f32x4 v11l = *reinterpret_cast<const f32x4*>(g11);
      const f32x4 v00h = *reinterpret_cast<const f32x4*>(g00 + 4);
      const f32x4 v01h = *reinterpret_cast<const f32x4*>(g01 + 4);
      const f32x4 v10h = *reinterpret_cast<const f32x4*>(g10 + 4);
      const f32x4 v11h = *reinterpret_cast<const f32x4*>(g11 + 4);

      const f32x4 topl = v00l + tx * (v01l - v00l);
      const f32x4 botl = v10l + tx * (v11l - v10l);
      const f32x4 pvl  = topl + ty * (botl - topl);
      const f32x4 toph = v00h + tx * (v01h - v00h);
      const f32x4 both = v10h + tx * (v11h - v10h);
      const f32x4 pvh  = toph + ty * (both - toph);

      float* orow = out + (size_t)grow * NDIM + gcol;
      *reinterpret_cast<f32x4*>(orow)     = c0 + bias_lo + pvl;
      *reinterpret_cast<f32x4*>(orow + 4) = c1 + bias_hi + pvh;
    }
  }
}

// ---------------- fallback: fp32 inputs, reg-stage + on-the-fly convert (known-good) ----
__global__ __launch_bounds__(256, 2)
void gemm_fb_kernel(const float* __restrict__ A,
                    const int*   __restrict__ ss,
                    const float* __restrict__ Wm,
                    const float* __restrict__ bias,
                    const float* __restrict__ pos,
                    float* __restrict__ out) {
  __shared__ unsigned short As[2][BM * BK];
  __shared__ unsigned short Bs[2][BM * BK];

  const int tid  = threadIdx.x;
  const int lane = tid & 63;
  const int wid  = tid >> 6;
  const int wr   = wid >> 1;
  const int wc   = wid & 1;

  const int bidh = blockIdx.x;
  const int bid  = (bidh & 7) * (GRID / 8) + (bidh >> 3);
  const int bm   = bid / NBN;
  const int bn   = bid % NBN;

  const int srow0 = tid >> 3;
  const int skc   = tid & 7;
  const float* Ag = A  + (size_t)(bm * BM + srow0) * KDIM + skc * 4;
  const float* Bg = Wm + (size_t)(bn * BN + srow0) * KDIM + skc * 4;

  float4 ra[4], rb[4];

  auto stage_load = [&](int kt) {
    const int ko = kt * BK;
#pragma unroll
    for (int r = 0; r < 4; ++r) {
      ra[r] = *reinterpret_cast<const float4*>(Ag + (size_t)(r * 32) * KDIM + ko);
      rb[r] = *reinterpret_cast<const float4*>(Bg + (size_t)(r * 32) * KDIM + ko);
    }
  };

  auto stage_write = [&](int buf) {
#pragma unroll
    for (int r = 0; r < 4; ++r) {
      const int arow = r * 32 + srow0;
      int off = arow * LDSROWB + skc * 8;
      off ^= (arow & 7) << 4;
      uint2 pa, pb;
      pa.x = pk2(ra[r].x, ra[r].y); pa.y = pk2(ra[r].z, ra[r].w);
      pb.x = pk2(rb[r].x, rb[r].y); pb.y = pk2(rb[r].z, rb[r].w);
      *reinterpret_cast<uint2*>(reinterpret_cast<char*>(&As[buf][0]) + off) = pa;
      *reinterpret_cast<uint2*>(reinterpret_cast<char*>(&Bs[buf][0]) + off) = pb;
    }
  };

  f32x4 acc[4][4];
#pragma unroll
  for (int i = 0; i < 4; ++i)
#pragma unroll
    for (int j = 0; j < 4; ++j) acc[i][j] = (f32x4)0.0f;

  const int fr = lane & 15;
  const int kg = lane >> 4;
  int abase = (wr * 64 + fr) * LDSROWB + kg * 16; abase ^= (fr & 7) << 4;
  int bbase = (wc * 64 + fr) * LDSROWB + kg * 16; bbase ^= (fr & 7) << 4;

  auto compute = [&](int buf) {
    const char* pa = reinterpret_cast<const char*>(&As[buf][0]);
    const char* pb = reinterpret_cast<const char*>(&Bs[buf][0]);
    bf16x8 af[4], bfv[4];
#pragma unroll
    for (int mf = 0; mf < 4; ++mf)
      af[mf] = *reinterpret_cast<const bf16x8*>(pa + abase + mf * 16 * LDSROWB);
#pragma unroll
    for (int nf = 0; nf < 4; ++nf)
      bfv[nf] = *reinterpret_cast<const bf16x8*>(pb + bbase + nf * 16 * LDSROWB);
#pragma unroll
    for (int mf = 0; mf < 4; ++mf)
#pragma unroll
      for (int nf = 0; nf < 4; ++nf)
        acc[mf][nf] = __builtin_amdgcn_mfma_f32_16x16x32_bf16(af[mf], bfv[nf], acc[mf][nf], 0, 0, 0);
  };

  stage_load(0);
  stage_write(0);
  for (int kt = 0; kt < NKT; ++kt) {
    const int cur = kt & 1;
    if (kt + 1 < NKT) stage_load(kt + 1);
    __syncthreads();
    compute(cur);
    if (kt + 1 < NKT) stage_write(cur ^ 1);
  }

  const int colbase = bn * BN + wc * 64 + fr;
  float bvals[4];
#pragma unroll
  for (int nf = 0; nf < 4; ++nf) bvals[nf] = bias[colbase + nf * 16];

  const int s  = bm >> 3;
  const int h  = ss[2 * s];
  const int w  = ss[2 * s + 1];
  const int hw = h * w;
  const float rh = 16.0f / (float)h;
  const float rw = 16.0f / (float)w;
  const int row0 = bm * BM + wr * 64 + kg * 4;

#pragma unroll
  for (int mf = 0; mf < 4; ++mf) {
#pragma unroll
    for (int rg = 0; rg < 4; ++rg) {
      const int row = row0 + mf * 16 + rg;
      int p = row & 1023;
      if (p >= hw) p = 0;
      const int y = p / w;
      const int x = p - y * w;
      const float fy = ((float)y + 0.5f) * rh - 0.5f;
      const float fx = ((float)x + 0.5f) * rw - 0.5f;
      const float yf = floorf(fy), xf = floorf(fx);
      const float ty = fy - yf,   tx = fx - xf;
      int iy0 = (int)yf, ix0 = (int)xf;
      int iy1 = iy0 + 1 > 15 ? 15 : iy0 + 1;
      int ix1 = ix0 + 1 > 15 ? 15 : ix0 + 1;
      iy0 = iy0 < 0 ? 0 : iy0;
      ix0 = ix0 < 0 ? 0 : ix0;
      const float* g00 = pos + (size_t)(iy0 * 16 + ix0) * NDIM;
      const float* g01 = pos + (size_t)(iy0 * 16 + ix1) * NDIM;
      const float* g10 = pos + (size_t)(iy1 * 16 + ix0) * NDIM;
      const float* g11 = pos + (size_t)(iy1 * 16 + ix1) * NDIM;
      float* orow = out + (size_t)row * NDIM;
#pragma unroll
      for (int nf = 0; nf < 4; ++nf) {
        const int col = colbase + nf * 16;
        const float p00 = g00[col], p01 = g01[col];
        const float p10 = g10[col], p11 = g11[col];
        const float top = p00 + tx * (p01 - p00);
        const float bot = p10 + tx * (p11 - p10);
        const float pv  = top + ty * (bot - top);
        orow[col] = acc[mf][nf][rg] + bvals[nf] + pv;
      }
    }
  }
}

extern "C" void kernel_launch(void* const* d_in, const int* in_sizes, int n_in,
                              void* d_out, int out_size, void* d_ws, size_t ws_size,
                              hipStream_t stream) {
  const float* A    = (const float*)d_in[0];
  const int*   ss   = (const int*)d_in[1];
  const float* Wm   = (const float*)d_in[2];
  const float* bias = (const float*)d_in[3];
  const float* pos  = (const float*)d_in[4];
  float* out = (float*)d_out;

  const size_t needA = (size_t)MDIM * KDIM * 2;  // 100,663,296 B
  const size_t needW = (size_t)NDIM * KDIM * 2;  //   1,769,472 B

  if (ws_size >= needA + needW) {
    __bf16* Ab = (__bf16*)d_ws;
    __bf16* Bb = (__bf16*)((char*)d_ws + needA);
    repack_all_kernel<<<(CHUNKS_A + CHUNKS_W) / 256, 256, 0, stream>>>(A, Ab, Wm, Bb);
    gemm_fm2_kernel<<<GRID, 256, 0, stream>>>(Ab, Bb, ss, bias, pos, out);
  } else {
    gemm_fb_kernel<<<GRID, 256, 0, stream>>>(A, ss, Wm, bias, pos, out);
  }
}